// Round 8
// baseline (423.414 us; speedup 1.0000x reference)
//
#include <hip/hip_runtime.h>
#include <math.h>

// VQVAE forward — R16: 16-rows/wave restructure. R15 evidence: conflicts
// halved AND barriers -36% => ZERO time change; both pipes ~36%, ~28%
// dependency stalls, 3 waves/SIMD. Occupancy model that fits all rounds:
// waves/SIMD = floor(512 / (VGPR+AGPR unified)). R12-R15: 84+64 = 148 -> 3.
// R11: (256,4) forced 128 onto a 148-reg workload -> catastrophic spill.
// Fix: halve the wave's register footprint honestly — 16 rows/wave
// (64 rows/block, grid 4096). acc2 32 AGPR, natural total ~110 -> fits
// launch_bounds(256,4) WITHOUT spill -> 4 waves/SIMD (50% occ).
// LDS re-laid to 24576 B (shared 8192-half staging region reused A->Z->C->E
// + 4x1024-half WPS; stride 32/64/128 rows + R15-proven XOR col-group
// swizzle) so LDS never re-binds occupancy. Extra barrier after Z-reads
// (staging region reuse). cnv-fold: accd initialized with -0.5*||c||^2 ->
// argmax score == argmin dist (saves 1 fma/element; rounding shift ~1e-6
// << 1e-4 scheme error << O(1) gaps -> zero argmin flips preserved).
// Precision scheme unchanged: fp16 split-2 enc+VQ, plain fp16 dec.

namespace {

constexpr int kN = 262144;

typedef _Float16 half8 __attribute__((ext_vector_type(8)));
typedef float floatx4 __attribute__((ext_vector_type(4)));

#define MFMA16(a, b, c) __builtin_amdgcn_mfma_f32_16x16x32_f16((a), (b), (c), 0, 0, 0)
#define LDS_FENCE() asm volatile("s_waitcnt lgkmcnt(0)" ::: "memory")
#define VMCNT0() asm volatile("s_waitcnt vmcnt(0)" ::: "memory")
#define BARRIER()                                  \
  do {                                             \
    asm volatile("" ::: "memory");                 \
    __builtin_amdgcn_s_barrier();                  \
    asm volatile("" ::: "memory");                 \
  } while (0)

// ---- workspace byte offsets (weights region, as R4-R15)
constexpr size_t W1M_O = 0;        // ew1 padded [256][32] f16 (k>=9 zero), main
constexpr size_t W1R_O = 16384;    // residual
constexpr size_t E2M_O = 32768;    // ew2 [128][256]
constexpr size_t E2R_O = 98304;
constexpr size_t E3M_O = 163840;   // ew3 [64][128]
constexpr size_t E3R_O = 180224;
constexpr size_t CBM_O = 196608;   // codebook [1024][64]
constexpr size_t CBR_O = 327680;
constexpr size_t D1P_O = 458752;   // dw1 [128][64] plain
constexpr size_t D2P_O = 475136;   // dw2 [256][128] plain
constexpr size_t D3P_O = 540672;   // dw3 padded [16][256] plain
constexpr size_t CN_O  = 548864;   // cn [1024] f32
// ---- small outputs (grid now 4096 -> esp 16384 floats)
constexpr size_t IDX_O = 589824;             // idx [N] i32 (1 MB)
constexpr size_t ESP_O = IDX_O + 1048576;    // es partials [16384] f32 (64 KB)
constexpr size_t HP_O  = ESP_O + 65536;      // hist partials [64][1024] i32

__device__ __forceinline__ void split2(float v, _Float16& hi, _Float16& lo) {
  hi = (_Float16)v;
  lo = (_Float16)(v - (float)hi);
}

// =====================================================================
__global__ void prep_kernel(
    const float* __restrict__ ew1, const float* __restrict__ ew2,
    const float* __restrict__ ew3, const float* __restrict__ cb,
    const float* __restrict__ dw1, const float* __restrict__ dw2,
    const float* __restrict__ dw3, char* __restrict__ wsb) {
  _Float16* w1m = (_Float16*)(wsb + W1M_O);
  _Float16* w1r = (_Float16*)(wsb + W1R_O);
  _Float16* e2m = (_Float16*)(wsb + E2M_O);
  _Float16* e2r = (_Float16*)(wsb + E2R_O);
  _Float16* e3m = (_Float16*)(wsb + E3M_O);
  _Float16* e3r = (_Float16*)(wsb + E3R_O);
  _Float16* cbm = (_Float16*)(wsb + CBM_O);
  _Float16* cbr = (_Float16*)(wsb + CBR_O);
  _Float16* d1p = (_Float16*)(wsb + D1P_O);
  _Float16* d2p = (_Float16*)(wsb + D2P_O);
  _Float16* d3p = (_Float16*)(wsb + D3P_O);
  float* cn = (float*)(wsb + CN_O);

  const int gid = blockIdx.x * 256 + threadIdx.x;
  const int stride = gridDim.x * 256;
  for (int e = gid; e < 256 * 32; e += stride) {
    int n = e >> 5, k = e & 31;
    float v = (k < 9) ? ew1[n * 9 + k] : 0.f;
    split2(v, w1m[e], w1r[e]);
  }
  for (int e = gid; e < 128 * 256; e += stride) split2(ew2[e], e2m[e], e2r[e]);
  for (int e = gid; e < 64 * 128; e += stride) split2(ew3[e], e3m[e], e3r[e]);
  for (int e = gid; e < 1024 * 64; e += stride) split2(cb[e], cbm[e], cbr[e]);
  for (int e = gid; e < 128 * 64; e += stride) d1p[e] = (_Float16)dw1[e];
  for (int e = gid; e < 256 * 128; e += stride) d2p[e] = (_Float16)dw2[e];
  for (int e = gid; e < 16 * 256; e += stride) {
    int n = e >> 8, k = e & 255;
    d3p[e] = (n < 9) ? (_Float16)dw3[n * 256 + k] : (_Float16)0.f;
  }
  for (int i = gid; i < 1024; i += stride) {
    float s = 0.f;
    const float* c = cb + (size_t)i * 64;
#pragma unroll 8
    for (int k = 0; k < 64; ++k) s = fmaf(c[k], c[k], s);
    cn[i] = s;
  }
}

// =====================================================================
// Megakernel: 64 rows/block, 4 waves x 16 rows. LDS 24576 B:
// STG = LP[0..8191] shared staging (A: W2 chunk hi/lo 4096+4096;
// Z: 4 x 2048 per-wave tiles; C: CB chunk hi/lo; E: WD2 chunk 8192),
// WPS = LP[8192 + w*1024], 1024 halves/wave.
__global__ __launch_bounds__(256, 4) void vqvae_mega(
    const float* __restrict__ x,
    const float* __restrict__ eb1, const float* __restrict__ eb2,
    const float* __restrict__ eb3, const float* __restrict__ db1,
    const float* __restrict__ db2, const float* __restrict__ db3,
    const float* __restrict__ cb, const char* __restrict__ wsb,
    float* __restrict__ out, int* __restrict__ idx_g, float* __restrict__ esp_g) {
  __shared__ _Float16 LP[12288];  // 24576 B

  const int t = threadIdx.x;
  const int lane = t & 63;
  const int w = t >> 6;
  const int m = lane & 15;
  const int q = lane >> 4;
  const int R0 = blockIdx.x * 64;
  const int row0 = R0 + w * 16;
  _Float16* WPS = LP + 8192 + w * 1024;
  _Float16* ZT = LP + w * 2048;
  const float* cn_g = (const float*)(wsb + CN_O);

  const int mh = m >> 3, ml = m & 7, m3 = m & 3, m7 = m & 7;
  const int rA = m * 32 + ((q ^ m3) << 3);  // 32-col tile read (row m, grp q)
  // 64-col tile read offsets (row m, K-group ks2*4+q):
  const int z0 = m * 64 + (((0 * 4 + q) ^ m7) << 3);
  const int z1 = m * 64 + (((1 * 4 + q) ^ m7) << 3);

  half8 axm = {}, axr = {};
  {
    const int grow = row0 + m;
    if (q == 0) {
#pragma unroll
      for (int j = 0; j < 8; ++j) {
        const float v = x[(size_t)grow * 9 + j];
        const _Float16 hi = (_Float16)v;
        axm[j] = hi;
        axr[j] = (_Float16)(v - (float)hi);
      }
    } else if (q == 1) {
      const float v = x[(size_t)grow * 9 + 8];
      const _Float16 hi = (_Float16)v;
      axm[0] = hi;
      axr[0] = (_Float16)(v - (float)hi);
    }
  }

  // ================= Stage A: enc1 fused with enc2 (staged W2, T14)
  floatx4 acc2[8];
#pragma unroll
  for (int nt = 0; nt < 8; ++nt) acc2[nt] = (floatx4){0.f, 0.f, 0.f, 0.f};

  {
    const int pA = t >> 7, nA = t & 127;
    const char* srcA = wsb + (pA ? E2R_O : E2M_O) + (size_t)nA * 512;
    _Float16* dstA = LP + pA * 4096 + nA * 32;
    const int sA = nA & 3;
    half8 stg[4];
#pragma unroll
    for (int j = 0; j < 4; ++j) stg[j] = *(const half8*)(srcA + j * 16);

    for (int kc = 0; kc < 8; ++kc) {
      VMCNT0();
#pragma unroll
      for (int j = 0; j < 4; ++j)
        *(half8*)(dstA + ((j ^ sA) << 3)) = stg[j];
      LDS_FENCE();
      if (kc < 7) {
#pragma unroll
        for (int j = 0; j < 4; ++j)
          stg[j] = *(const half8*)(srcA + (size_t)(kc + 1) * 64 + j * 16);
      }
      BARRIER();

#pragma unroll
      for (int ntl = 0; ntl < 2; ++ntl) {
        const int f = kc * 32 + ntl * 16 + m;
        const half8 bm = *(const half8*)(wsb + W1M_O + (size_t)f * 64 + q * 16);
        const half8 br = *(const half8*)(wsb + W1R_O + (size_t)f * 64 + q * 16);
        const float bias = eb1[f];
        floatx4 a = (floatx4){0.f, 0.f, 0.f, 0.f};
        a = MFMA16(axr, bm, a);
        a = MFMA16(axm, br, a);
        a = MFMA16(axm, bm, a);
#pragma unroll
        for (int reg = 0; reg < 4; ++reg) {
          const float v = fmaxf(a[reg] + bias, 0.f);
          const int r = 4 * q + reg;
          const int g = (ntl * 2 + mh) ^ reg;  // r&3 == reg
          const _Float16 hi = (_Float16)v;
          WPS[r * 32 + (g << 3) + ml] = hi;
          WPS[512 + r * 32 + (g << 3) + ml] = (_Float16)(v - (float)hi);
        }
      }
      LDS_FENCE();
      const half8 am = *(const half8*)(WPS + rA);
      const half8 ar = *(const half8*)(WPS + 512 + rA);
      __builtin_amdgcn_s_setprio(1);
#pragma unroll
      for (int nt = 0; nt < 8; ++nt) {
        const half8 bm = *(const half8*)(LP + nt * 512 + rA);
        const half8 br = *(const half8*)(LP + 4096 + nt * 512 + rA);
        acc2[nt] = MFMA16(ar, bm, acc2[nt]);
        acc2[nt] = MFMA16(am, br, acc2[nt]);
        acc2[nt] = MFMA16(am, bm, acc2[nt]);
      }
      __builtin_amdgcn_s_setprio(0);
      BARRIER();  // staged reads done -> next chunk may overwrite
    }
  }

  // ================= Stage B: enc3 (B direct from L2; H2 via WPS)
  floatx4 acc3[4];
#pragma unroll
  for (int nt = 0; nt < 4; ++nt) acc3[nt] = (floatx4){0.f, 0.f, 0.f, 0.f};

  for (int ks = 0; ks < 4; ++ks) {
#pragma unroll
    for (int h = 0; h < 2; ++h) {
      const int nt = 2 * ks + h;
      const float bias = eb2[nt * 16 + m];
#pragma unroll
      for (int reg = 0; reg < 4; ++reg) {
        const float v = fmaxf(acc2[nt][reg] + bias, 0.f);
        const int r = 4 * q + reg;
        const int g = (h * 2 + mh) ^ reg;
        const _Float16 hi = (_Float16)v;
        WPS[r * 32 + (g << 3) + ml] = hi;
        WPS[512 + r * 32 + (g << 3) + ml] = (_Float16)(v - (float)hi);
      }
    }
    LDS_FENCE();
    const half8 am = *(const half8*)(WPS + rA);
    const half8 ar = *(const half8*)(WPS + 512 + rA);
#pragma unroll
    for (int nt = 0; nt < 4; ++nt) {
      const half8 bm = *(const half8*)(wsb + E3M_O + (size_t)(nt * 16 + m) * 256 + ks * 64 + q * 16);
      const half8 br = *(const half8*)(wsb + E3R_O + (size_t)(nt * 16 + m) * 256 + ks * 64 + q * 16);
      acc3[nt] = MFMA16(ar, bm, acc3[nt]);
      acc3[nt] = MFMA16(am, br, acc3[nt]);
      acc3[nt] = MFMA16(am, bm, acc3[nt]);
    }
  }

  // ---- Stage C prologue: issue chunk-0 codebook loads (hide under Z)
  const int pC = t >> 7, eC = t & 127;
  const int nC = eC >> 1, hC = eC & 1;
  const char* srcC = wsb + (pC ? CBR_O : CBM_O) + (size_t)nC * 128 + hC * 64;
  _Float16* dstC = LP + pC * 4096 + nC * 64;
  const int sC = nC & 7;
  half8 stgC[4];
#pragma unroll
  for (int j = 0; j < 4; ++j) stgC[j] = *(const half8*)(srcC + j * 16);

  // ---- Z epilogue -> register fragments (Z tile in per-wave STG region;
  // safe: stage A's final barrier drained all staged-W2 reads)
  half8 zfm[2], zfr[2];
#pragma unroll
  for (int nt = 0; nt < 4; ++nt) {
    const float bias = eb3[nt * 16 + m];
#pragma unroll
    for (int reg = 0; reg < 4; ++reg) {
      const float v = acc3[nt][reg] + bias;
      const int r = 4 * q + reg;
      const int g = (nt * 2 + mh) ^ (r & 7);
      const _Float16 hi = (_Float16)v;
      ZT[r * 64 + (g << 3) + ml] = hi;
      ZT[1024 + r * 64 + (g << 3) + ml] = (_Float16)(v - (float)hi);
    }
  }
  LDS_FENCE();
  zfm[0] = *(const half8*)(ZT + z0);
  zfr[0] = *(const half8*)(ZT + 1024 + z0);
  zfm[1] = *(const half8*)(ZT + z1);
  zfr[1] = *(const half8*)(ZT + 1024 + z1);
  BARRIER();  // all waves' Z reads done before C staging overwrites STG

  // ================= Stage C: VQ argmax-score (staged CB, cnv folded)
  float bests[4];
  int besti[4];
#pragma unroll
  for (int reg = 0; reg < 4; ++reg) { bests[reg] = -3.4e38f; besti[reg] = 0; }

  for (int cc = 0; cc < 16; ++cc) {
    VMCNT0();
#pragma unroll
    for (int j = 0; j < 4; ++j)
      *(half8*)(dstC + (((hC * 4 + j) ^ sC) << 3)) = stgC[j];
    LDS_FENCE();
    if (cc < 15) {
#pragma unroll
      for (int j = 0; j < 4; ++j)
        stgC[j] = *(const half8*)(srcC + (size_t)(cc + 1) * 8192 + j * 16);
    }
    BARRIER();

    floatx4 accd[4];
#pragma unroll
    for (int nt = 0; nt < 4; ++nt) {
      const float ci = -0.5f * cn_g[cc * 64 + nt * 16 + m];
      accd[nt] = (floatx4){ci, ci, ci, ci};
    }
    __builtin_amdgcn_s_setprio(1);
#pragma unroll
    for (int nt = 0; nt < 4; ++nt) {
      const half8 bm0 = *(const half8*)(LP + nt * 1024 + z0);
      const half8 br0 = *(const half8*)(LP + 4096 + nt * 1024 + z0);
      accd[nt] = MFMA16(zfr[0], bm0, accd[nt]);
      accd[nt] = MFMA16(zfm[0], br0, accd[nt]);
      accd[nt] = MFMA16(zfm[0], bm0, accd[nt]);
      const half8 bm1 = *(const half8*)(LP + nt * 1024 + z1);
      const half8 br1 = *(const half8*)(LP + 4096 + nt * 1024 + z1);
      accd[nt] = MFMA16(zfr[1], bm1, accd[nt]);
      accd[nt] = MFMA16(zfm[1], br1, accd[nt]);
      accd[nt] = MFMA16(zfm[1], bm1, accd[nt]);
    }
    __builtin_amdgcn_s_setprio(0);
#pragma unroll
    for (int nt = 0; nt < 4; ++nt) {
      const int code = cc * 64 + nt * 16 + m;
#pragma unroll
      for (int reg = 0; reg < 4; ++reg) {
        const float s = accd[nt][reg];  // score = dot - 0.5||c||^2 (maximize)
        if (s > bests[reg]) { bests[reg] = s; besti[reg] = code; }
      }
    }
    BARRIER();  // staged reads done -> next chunk may overwrite
  }
#pragma unroll
  for (int reg = 0; reg < 4; ++reg) {
#pragma unroll
    for (int off = 1; off < 16; off <<= 1) {
      const float os = __shfl_xor(bests[reg], off, 16);
      const int oi = __shfl_xor(besti[reg], off, 16);
      if (os > bests[reg] || (os == bests[reg] && oi < besti[reg])) {
        bests[reg] = os; besti[reg] = oi;
      }
    }
  }
  if (m == 0) {
#pragma unroll
    for (int reg = 0; reg < 4; ++reg)
      idx_g[row0 + 4 * q + reg] = besti[reg];  // plain store; hist follows
  }

  // ---- z_q + per-wave e_latent partial. After the width-16 butterfly all
  // lanes in a q-group hold that group's argmin. Row m -> group m>>2, reg m&3.
  const int sl = ((m >> 2) << 4) | m;
  half8 zq[2];
  float es = 0.f;
  {
    const int b0 = __shfl(besti[0], sl);
    const int b1 = __shfl(besti[1], sl);
    const int b2 = __shfl(besti[2], sl);
    const int b3v = __shfl(besti[3], sl);
    const int r2 = m & 3;
    const int bi = (r2 == 0) ? b0 : (r2 == 1) ? b1 : (r2 == 2) ? b2 : b3v;
#pragma unroll
    for (int ks2 = 0; ks2 < 2; ++ks2) {
      const float* cp = cb + (size_t)bi * 64 + ks2 * 32 + q * 8;
      const float4 c0 = *(const float4*)cp;
      const float4 c1 = *(const float4*)(cp + 4);
      float cv[8] = {c0.x, c0.y, c0.z, c0.w, c1.x, c1.y, c1.z, c1.w};
#pragma unroll
      for (int j = 0; j < 8; ++j) {
        const float z = (float)zfm[ks2][j] + (float)zfr[ks2][j];
        const float d = cv[j] - z;
        es = fmaf(d, d, es);
        zq[ks2][j] = (_Float16)(z + d);
      }
    }
  }
#pragma unroll
  for (int off = 1; off < 64; off <<= 1) es += __shfl_xor(es, off, 64);
  if (lane == 0) esp_g[blockIdx.x * 4 + w] = es;  // no atomic

  // ---- Stage E prologue: issue chunk-0 WD2 loads (hide under stage D)
  const int nE = t >> 2, jE = t & 3;
  const char* srcE = wsb + D2P_O + (size_t)nE * 256 + jE * 64;
  _Float16* dstE = LP + nE * 128;
  const int sE = nE & 15;
  half8 stgE[4];
#pragma unroll
  for (int j = 0; j < 4; ++j) stgE[j] = *(const half8*)(srcE + j * 16);

  // ================= Stage D: dec1 (plain fp16, B direct)
  floatx4 accH[8];
#pragma unroll
  for (int nt = 0; nt < 8; ++nt) accH[nt] = (floatx4){0.f, 0.f, 0.f, 0.f};
  __builtin_amdgcn_s_setprio(1);
#pragma unroll
  for (int nt = 0; nt < 8; ++nt) {
#pragma unroll
    for (int ks2 = 0; ks2 < 2; ++ks2) {
      const half8 b = *(const half8*)(wsb + D1P_O + (size_t)(nt * 16 + m) * 128 + ks2 * 64 + q * 16);
      accH[nt] = MFMA16(zq[ks2], b, accH[nt]);
    }
  }
  __builtin_amdgcn_s_setprio(0);
  half8 h3f[4];
  for (int ks = 0; ks < 4; ++ks) {
#pragma unroll
    for (int h = 0; h < 2; ++h) {
      const int nt = 2 * ks + h;
      const float bias = db1[nt * 16 + m];
#pragma unroll
      for (int reg = 0; reg < 4; ++reg) {
        const float v = fmaxf(accH[nt][reg] + bias, 0.f);
        const int r = 4 * q + reg;
        const int g = (h * 2 + mh) ^ reg;
        WPS[r * 32 + (g << 3) + ml] = (_Float16)v;
      }
    }
    LDS_FENCE();
    h3f[ks] = *(const half8*)(WPS + rA);
  }

  // ================= Stage E: dec2 (staged WD2) fused with dec3
  floatx4 accO = (floatx4){0.f, 0.f, 0.f, 0.f};
  for (int jc = 0; jc < 4; ++jc) {
    VMCNT0();
#pragma unroll
    for (int j = 0; j < 4; ++j)
      *(half8*)(dstE + (((jE * 4 + j) ^ sE) << 3)) = stgE[j];
    LDS_FENCE();
    if (jc < 3) {
#pragma unroll
      for (int j = 0; j < 4; ++j)
        stgE[j] = *(const half8*)(srcE + (size_t)(jc + 1) * 16384 + j * 16);
    }
    BARRIER();

    floatx4 accD2[4];
#pragma unroll
    for (int nt = 0; nt < 4; ++nt) accD2[nt] = (floatx4){0.f, 0.f, 0.f, 0.f};
    __builtin_amdgcn_s_setprio(1);
#pragma unroll
    for (int nt = 0; nt < 4; ++nt) {
      const int n2 = nt * 16 + m;
#pragma unroll
      for (int ks = 0; ks < 4; ++ks) {
        const half8 b = *(const half8*)(LP + n2 * 128 + (((ks * 4 + q) ^ m) << 3));
        accD2[nt] = MFMA16(h3f[ks], b, accD2[nt]);
      }
    }
    __builtin_amdgcn_s_setprio(0);
    half8 b3[2];
#pragma unroll
    for (int ks2 = 0; ks2 < 2; ++ks2)
      b3[ks2] = *(const half8*)(wsb + D3P_O + (size_t)m * 512 + jc * 128 + ks2 * 64 + q * 16);
#pragma unroll
    for (int nt = 0; nt < 4; ++nt) {
      const float bias = db2[jc * 64 + nt * 16 + m];
#pragma unroll
      for (int reg = 0; reg < 4; ++reg) {
        const float v = fmaxf(accD2[nt][reg] + bias, 0.f);
        const int r = 4 * q + reg;
        const int g = (nt * 2 + mh) ^ (r & 7);
        WPS[r * 64 + (g << 3) + ml] = (_Float16)v;
      }
    }
    LDS_FENCE();
    {
      const half8 a0 = *(const half8*)(WPS + z0);
      accO = MFMA16(a0, b3[0], accO);
      const half8 a1 = *(const half8*)(WPS + z1);
      accO = MFMA16(a1, b3[1], accO);
    }
    BARRIER();  // staged reads done -> next chunk may overwrite
  }
  if (m < 9) {
    const float bias = db3[m];
#pragma unroll
    for (int reg = 0; reg < 4; ++reg) {
      const size_t r = (size_t)(row0 + 4 * q + reg);
      out[r * 9 + m] = accO[reg] + bias;
    }
  }
}

// =====================================================================
__global__ __launch_bounds__(256) void hist_kernel(
    const int* __restrict__ idx_g, int* __restrict__ hp) {
  __shared__ int lh[1024];
  const int t = threadIdx.x;
#pragma unroll
  for (int i = 0; i < 4; ++i) lh[t * 4 + i] = 0;
  __syncthreads();
  for (int i = t; i < 4096; i += 256)
    atomicAdd(&lh[idx_g[blockIdx.x * 4096 + i]], 1);  // LDS atomic only
  __syncthreads();
  int* part = hp + blockIdx.x * 1024;
#pragma unroll
  for (int i = 0; i < 4; ++i) part[t * 4 + i] = lh[t * 4 + i];
}

// =====================================================================
__global__ __launch_bounds__(1024) void finalize_kernel(
    const int* __restrict__ hp, const float* __restrict__ esp,
    float* __restrict__ out2) {
  __shared__ double red[1024];
  __shared__ float rede[1024];
  const int t = threadIdx.x;
  int h = 0;
#pragma unroll 8
  for (int p = 0; p < 64; ++p) h += hp[p * 1024 + t];
  const float pr = (float)h * (1.0f / (float)kN);
  red[t] = (double)(pr * logf(pr + 1e-10f));
  float es = 0.f;
#pragma unroll
  for (int i = 0; i < 16; ++i) es += esp[i * 1024 + t];
  rede[t] = es;
  __syncthreads();
  for (int s = 512; s > 0; s >>= 1) {
    if (t < s) { red[t] += red[t + s]; rede[t] += rede[t + s]; }
    __syncthreads();
  }
  if (t == 0) {
    out2[0] = 1.25f * (rede[0] * (1.0f / ((float)kN * 64.0f)));
    out2[1] = expf((float)(-red[0]));
  }
}

}  // namespace

extern "C" void kernel_launch(void* const* d_in, const int* in_sizes, int n_in,
                              void* d_out, int out_size, void* d_ws, size_t ws_size,
                              hipStream_t stream) {
  const float* x   = (const float*)d_in[0];
  const float* ew1 = (const float*)d_in[1];
  const float* eb1 = (const float*)d_in[2];
  const float* ew2 = (const float*)d_in[3];
  const float* eb2 = (const float*)d_in[4];
  const float* ew3 = (const float*)d_in[5];
  const float* eb3 = (const float*)d_in[6];
  const float* dw1 = (const float*)d_in[7];
  const float* db1 = (const float*)d_in[8];
  const float* dw2 = (const float*)d_in[9];
  const float* db2 = (const float*)d_in[10];
  const float* dw3 = (const float*)d_in[11];
  const float* db3 = (const float*)d_in[12];
  const float* cb  = (const float*)d_in[13];
  float* out = (float*)d_out;
  char* wsb = (char*)d_ws;

  int* idx_g = (int*)(wsb + IDX_O);
  float* esp = (float*)(wsb + ESP_O);
  int* hp = (int*)(wsb + HP_O);

  prep_kernel<<<128, 256, 0, stream>>>(ew1, ew2, ew3, cb, dw1, dw2, dw3, wsb);
  vqvae_mega<<<kN / 64, 256, 0, stream>>>(x, eb1, eb2, eb3, db1, db2, db3, cb,
                                          wsb, out, idx_g, esp);
  hist_kernel<<<64, 256, 0, stream>>>(idx_g, hp);
  finalize_kernel<<<1, 1024, 0, stream>>>(hp, esp, out + (size_t)kN * 9);
}